// Round 2
// baseline (845.874 us; speedup 1.0000x reference)
//
#include <hip/hip_runtime.h>
#include <hip/hip_cooperative_groups.h>
#include <math.h>

namespace cg = cooperative_groups;

// Problem constants (fixed shapes from reference):
//   x: [1, 512, 448, 448] fp32; boost_weight: [512, 512] fp32
#define NCH     512
#define HW      200704        // 448*448
#define HW4     50176         // HW/4 (float4 per channel)
#define X_ELEMS 102760448ULL  // 512*200704
#define CITERS  196           // HW4 / 256 threads

typedef float vf4 __attribute__((ext_vector_type(4)));

// ===========================================================================
// Shared helpers
// ===========================================================================
__device__ __forceinline__ float block_reduce_sum256(float v, float* red) {
    #pragma unroll
    for (int o = 32; o > 0; o >>= 1) v += __shfl_down(v, o, 64);
    const int wave = threadIdx.x >> 6;
    const int lane = threadIdx.x & 63;
    if (lane == 0) red[wave] = v;
    __syncthreads();
    float r = (red[0] + red[1]) + (red[2] + red[3]);
    __syncthreads();
    return r;
}

__device__ __forceinline__ float block_reduce_max256(float v, float* red) {
    #pragma unroll
    for (int o = 32; o > 0; o >>= 1) v = fmaxf(v, __shfl_down(v, o, 64));
    const int wave = threadIdx.x >> 6;
    const int lane = threadIdx.x & 63;
    if (lane == 0) red[wave] = v;
    __syncthreads();
    float r = fmaxf(fmaxf(red[0], red[1]), fmaxf(red[2], red[3]));
    __syncthreads();
    return r;
}

// ===========================================================================
// PRIMARY PATH: one cooperative kernel, 512 blocks (1 channel each), 2 syncs.
//   P1: channel mean (forward read -> slice tail is L3-hot)
//   P2: boost_vec[c] = W[c,:] . avr
//   P3: stats computed REDUNDANTLY per block (512-elem reductions, cheap),
//       then weight row c + rescale of own channel in REVERSE (freshest
//       bytes consumed first; NT stores keep out-stream from evicting x).
// ws layout: [0,512) channel means; [512,1024) boost_vec.
// ===========================================================================
__global__ __launch_bounds__(256, 2) void k_coop(const float* __restrict__ x,
                                                 const float* __restrict__ W,
                                                 float* __restrict__ ws,
                                                 float* __restrict__ out,
                                                 float* __restrict__ outW) {
    __shared__ float red[4];
    __shared__ float avr_s[NCH];
    __shared__ float bv_s[NCH];
    __shared__ float xt_s[NCH];
    __shared__ float xs_s[NCH];
    cg::grid_group grid = cg::this_grid();

    const int c = blockIdx.x;
    const int t = threadIdx.x;
    const float4* xv = reinterpret_cast<const float4*>(x) + (size_t)c * HW4;

    // ---- P1: channel sum (4-way unroll for MLP) ----
    {
        float s0 = 0.f, s1 = 0.f, s2 = 0.f, s3 = 0.f;
        for (int i = 0; i < CITERS; i += 4) {
            float4 a = xv[(size_t)(i + 0) * 256 + t];
            float4 b = xv[(size_t)(i + 1) * 256 + t];
            float4 cc = xv[(size_t)(i + 2) * 256 + t];
            float4 d = xv[(size_t)(i + 3) * 256 + t];
            s0 += (a.x + a.y) + (a.z + a.w);
            s1 += (b.x + b.y) + (b.z + b.w);
            s2 += (cc.x + cc.y) + (cc.z + cc.w);
            s3 += (d.x + d.y) + (d.z + d.w);
        }
        float ssum = block_reduce_sum256((s0 + s1) + (s2 + s3), red);
        if (t == 0) ws[c] = ssum * (1.0f / (float)HW);
    }
    grid.sync();

    // ---- P2: boost_vec[c] = W[c,:] . avr ----
    {
        #pragma unroll
        for (int j = t; j < NCH; j += 256) avr_s[j] = ws[j];
        __syncthreads();
        const float* row = W + (size_t)c * NCH;
        float acc = row[t] * avr_s[t] + row[t + 256] * avr_s[t + 256];
        float bv = block_reduce_sum256(acc, red);
        if (t == 0) ws[NCH + c] = bv;
    }
    grid.sync();

    // ---- P3: redundant per-block stats over the 512-vector ----
    #pragma unroll
    for (int j = t; j < NCH; j += 256) bv_s[j] = ws[NCH + j];
    __syncthreads();

    const float a0 = avr_s[t],       a1 = avr_s[t + 256];
    const float bv0 = bv_s[t],       bv1 = bv_s[t + 256];

    const float inh = block_reduce_sum256(bv0 + bv1, red) * (1.0f / (float)NCH);
    float xt0 = fmaxf(a0 + bv0 - 2.0f * inh, 0.f);
    float xt1 = fmaxf(a1 + bv1 - 2.0f * inh, 0.f);

    const float thr = block_reduce_max256(fmaxf(xt0, xt1), red) * 0.9f;
    const float xs0 = (xt0 < thr) ? 0.f : xt0;
    const float xs1 = (xt1 < thr) ? 0.f : xt1;

    // ||outer(xt,xs), diag=0||^2 = (sum xt^2)(sum xs^2) - sum (xt*xs)^2
    const float sa = block_reduce_sum256(xt0 * xt0 + xt1 * xt1, red);
    const float sb = block_reduce_sum256(xs0 * xs0 + xs1 * xs1, red);
    const float d0 = xt0 * xs0, d1 = xt1 * xs1;
    const float sd = block_reduce_sum256(d0 * d0 + d1 * d1, red);
    const float n2 = sa * sb - sd;
    const float norm = (n2 > 0.f) ? sqrtf(n2) : 0.f;
    const float inv = (norm > 0.f && isfinite(norm)) ? (1.0f / norm) : 1.0f;

    xt_s[t] = xt0; xt_s[t + 256] = xt1;
    xs_s[t] = xs0; xs_s[t + 256] = xs1;
    __syncthreads();

    // ---- P3a: weight row c ----
    {
        const float xtc = xt_s[c];
        const float* wrow = W + (size_t)c * NCH;
        float* orow = outW + (size_t)c * NCH;
        #pragma unroll
        for (int j = t; j < NCH; j += 256) {
            const float v = (j == c) ? 0.f : xtc * xs_s[j] * inv;
            orow[j] = 0.5f * wrow[j] + 0.05f * v;
        }
    }

    // ---- P3b: rescale own channel in REVERSE (freshest bytes first) ----
    {
        const float s = xt_s[c] / (avr_s[c] + 1e-12f);
        float4* ov = reinterpret_cast<float4*>(out) + (size_t)c * HW4;
        for (int i = CITERS - 2; i >= 0; i -= 2) {
            const size_t o1 = (size_t)(i + 1) * 256 + t;
            const size_t o0 = (size_t)i * 256 + t;
            float4 a = xv[o1];
            float4 b = xv[o0];
            a.x *= s; a.y *= s; a.z *= s; a.w *= s;
            b.x *= s; b.y *= s; b.z *= s; b.w *= s;
            __builtin_nontemporal_store(*(const vf4*)&a, (vf4*)&ov[o1]);
            __builtin_nontemporal_store(*(const vf4*)&b, (vf4*)&ov[o0]);
        }
    }
}

// ===========================================================================
// FALLBACK PATH: round-0 three-kernel pipeline (known-good, 758 us).
// ws layout (floats): [0,4096) partials; [4096,4608) x_tmp; [4608,5120)
// x_sparse; [5120,5632) scale; [5632] inv_norm.
// ===========================================================================
#define GROUPS 8
#define G4     6272
#define WS_XTMP  4096
#define WS_XSP   4608
#define WS_SCALE 5120
#define WS_INV   5632

__global__ __launch_bounds__(256) void k_mean_partial(const float* __restrict__ x,
                                                      float* __restrict__ ws) {
    __shared__ float red[4];
    const int g = blockIdx.x;
    const int c = blockIdx.y;
    const float4* xv = reinterpret_cast<const float4*>(x) + (size_t)c * HW4 + (size_t)g * G4;
    float s = 0.f;
    for (int i = threadIdx.x; i < G4; i += 256) {
        float4 v = xv[i];
        s += (v.x + v.y) + (v.z + v.w);
    }
    #pragma unroll
    for (int o = 32; o > 0; o >>= 1) s += __shfl_down(s, o, 64);
    const int wave = threadIdx.x >> 6;
    const int lane = threadIdx.x & 63;
    if (lane == 0) red[wave] = s;
    __syncthreads();
    if (threadIdx.x == 0) ws[g * NCH + c] = (red[0] + red[1]) + (red[2] + red[3]);
}

__global__ __launch_bounds__(512) void k_stats(const float* __restrict__ W,
                                               float* __restrict__ ws) {
    __shared__ float avr[512];
    __shared__ float red[8];
    __shared__ float redA[8], redB[8], redD[8];
    __shared__ float bcast;

    const int t = threadIdx.x;
    const int wave = t >> 6;
    const int lane = t & 63;

    {
        float s = 0.f;
        #pragma unroll
        for (int g = 0; g < GROUPS; ++g) s += ws[g * NCH + t];
        avr[t] = s * (1.0f / (float)HW);
    }
    __syncthreads();

    float acc = 0.f;
    const float* row = W + (size_t)t * NCH;
    #pragma unroll 8
    for (int j = 0; j < NCH; ++j) acc += row[j] * avr[j];

    float s = acc;
    #pragma unroll
    for (int o = 32; o > 0; o >>= 1) s += __shfl_down(s, o, 64);
    if (lane == 0) red[wave] = s;
    __syncthreads();
    if (t == 0) {
        float tt = 0.f;
        #pragma unroll
        for (int w = 0; w < 8; ++w) tt += red[w];
        bcast = tt * (1.0f / (float)NCH);
    }
    __syncthreads();
    const float inh = bcast;

    float xtmp = avr[t] + acc - 2.0f * inh;
    xtmp = xtmp > 0.f ? xtmp : 0.f;

    float m = xtmp;
    #pragma unroll
    for (int o = 32; o > 0; o >>= 1) m = fmaxf(m, __shfl_down(m, o, 64));
    __syncthreads();
    if (lane == 0) red[wave] = m;
    __syncthreads();
    if (t == 0) {
        float mm = red[0];
        #pragma unroll
        for (int w = 1; w < 8; ++w) mm = fmaxf(mm, red[w]);
        bcast = mm * 0.9f;
    }
    __syncthreads();
    const float thr = bcast;
    const float xs = (xtmp < thr) ? 0.f : xtmp;

    float a = xtmp * xtmp;
    float b = xs * xs;
    float d = xtmp * xs; d = d * d;
    #pragma unroll
    for (int o = 32; o > 0; o >>= 1) {
        a += __shfl_down(a, o, 64);
        b += __shfl_down(b, o, 64);
        d += __shfl_down(d, o, 64);
    }
    if (lane == 0) { redA[wave] = a; redB[wave] = b; redD[wave] = d; }
    __syncthreads();
    if (t == 0) {
        float s1 = 0.f, s2 = 0.f, s3 = 0.f;
        #pragma unroll
        for (int w = 0; w < 8; ++w) { s1 += redA[w]; s2 += redB[w]; s3 += redD[w]; }
        float n2 = s1 * s2 - s3;
        float norm = (n2 > 0.f) ? sqrtf(n2) : 0.f;
        ws[WS_INV] = (norm > 0.f && isfinite(norm)) ? (1.0f / norm) : 1.0f;
    }

    ws[WS_XTMP + t]  = xtmp;
    ws[WS_XSP + t]   = xs;
    ws[WS_SCALE + t] = xtmp / (avr[t] + 1e-12f);
}

__global__ __launch_bounds__(256) void k_tail(const float* __restrict__ x,
                                              const float* __restrict__ W,
                                              const float* __restrict__ ws,
                                              float* __restrict__ out,
                                              float* __restrict__ outW) {
    const int bid = blockIdx.x;
    if (bid < 1024) {
        const int idx = bid * 256 + threadIdx.x;
        const int i = idx >> 9;
        const int j = idx & (NCH - 1);
        const float inv = ws[WS_INV];
        const float v = (i == j) ? 0.f : ws[WS_XTMP + i] * ws[WS_XSP + j] * inv;
        outW[idx] = 0.5f * W[idx] + 0.05f * v;
    } else {
        const int b = bid - 1024;
        const int c_lin = b / 49;
        const int t = b - c_lin * 49;
        const int c = (NCH - 1) - c_lin;
        const float s = ws[WS_SCALE + c];
        const size_t chan_base = (size_t)c * HW4;
        const int base = t * 1024 + threadIdx.x;
        const float4* xv = reinterpret_cast<const float4*>(x);
        float4* ov = reinterpret_cast<float4*>(out);
        #pragma unroll
        for (int k = 0; k < 4; ++k) {
            const size_t off = chan_base + (size_t)(base + k * 256);
            float4 v = xv[off];
            v.x *= s; v.y *= s; v.z *= s; v.w *= s;
            __builtin_nontemporal_store(*(const vf4*)&v, (vf4*)&ov[off]);
        }
    }
}

// ===========================================================================
extern "C" void kernel_launch(void* const* d_in, const int* in_sizes, int n_in,
                              void* d_out, int out_size, void* d_ws, size_t ws_size,
                              hipStream_t stream) {
    const float* x = (const float*)d_in[0];
    const float* W = (const float*)d_in[1];
    float* out  = (float*)d_out;
    float* outW = out + X_ELEMS;   // new_boost_weight follows out in flat order
    float* ws   = (float*)d_ws;

    void* args[] = {(void*)&x, (void*)&W, (void*)&ws, (void*)&out, (void*)&outW};
    hipError_t e = hipLaunchCooperativeKernel((void*)k_coop, dim3(NCH), dim3(256),
                                              args, 0, stream);
    if (e == hipSuccess) return;

    (void)hipGetLastError();   // clear the failed-launch error state

    // Fallback: known-good three-kernel pipeline.
    dim3 grid_mean(GROUPS, NCH);
    k_mean_partial<<<grid_mean, 256, 0, stream>>>(x, ws);
    k_stats<<<1, 512, 0, stream>>>(W, ws);
    k_tail<<<1024 + 49 * NCH, 256, 0, stream>>>(x, W, ws, out, outW);
}